// Round 6
// baseline (143.172 us; speedup 1.0000x reference)
//
#include <hip/hip_runtime.h>
#include <stdint.h>

// Problem constants (fixed by reference)
#define NTOK 8192
#define DM   1024
#define NE   8
#define NR   16
#define KX   1152   // DM + NE*NR = 1024 + 128

typedef short bf16x8 __attribute__((ext_vector_type(8)));
typedef float f32x4  __attribute__((ext_vector_type(4)));

__device__ __forceinline__ unsigned short f2bf(float f) {
    union { float f; unsigned u; } v; v.f = f;
    unsigned r = v.u + 0x7fffu + ((v.u >> 16) & 1u);   // RNE
    return (unsigned short)(r >> 16);
}

__device__ __forceinline__ void gld16(const void* g, void* l) {
    __builtin_amdgcn_global_load_lds((__attribute__((address_space(1))) void*)g,
                                     (__attribute__((address_space(3))) void*)l,
                                     16, 0, 0);
}

// ---------------------------------------------------------------------------
// wprep: weight conversions only.
//  blocks [0,1024):    WBext[j][0:1152] = [W_base[j][:] | B[:, j]]  (bf16)
//  blocks [1024,1152): At[p][0:1024] = A[e][:][r] transpose         (bf16)
// ---------------------------------------------------------------------------
__global__ __launch_bounds__(256) void wprep(const float* __restrict__ Asrc,
                                             const float* __restrict__ Bsrc,
                                             const float* __restrict__ Wb,
                                             unsigned short* __restrict__ WBext,
                                             unsigned short* __restrict__ At) {
    const int b = blockIdx.x;
    const int t = threadIdx.x;
    if (b < 1024) {
        const int j = b;
        unsigned short* row = WBext + (size_t)j * KX;
        float4 v = ((const float4*)(Wb + (size_t)j * DM))[t];
        ushort4 o;
        o.x = f2bf(v.x); o.y = f2bf(v.y); o.z = f2bf(v.z); o.w = f2bf(v.w);
        *(ushort4*)(row + t * 4) = o;
        if (t < 128) row[DM + t] = f2bf(Bsrc[(size_t)t * DM + j]);   // B[e][r][j]
    } else {
        const int p = b - 1024;            // 0..127
        const int e = p >> 4, r = p & 15;
        for (int d = t; d < DM; d += 256)
            At[(size_t)p * DM + d] = f2bf(Asrc[e * (DM * NR) + d * NR + r]);
    }
}

// ---------------------------------------------------------------------------
// gmoe: fused per-32-token-tile kernel. Reads x fp32 ONCE; per K-chunk of 64:
//   - converts x to bf16 -> LDS (XOR-swizzled) and -> Xext[:,0:1024]
//   - accumulates fp32 gating logits (per-thread 8-col slice, VALU)
//   - stages At chunk via global_load_lds (XOR-swizzled)
//   - MFMA x @ At^T (hall structure)
// Epilogue: 8-lane butterfly logit reduce, top-2 softmax -> combine in LDS,
//   scale H by combine, write bf16 H -> Xext[:,1024:1152].
// ---------------------------------------------------------------------------
__global__ __launch_bounds__(256) void gmoe(const float* __restrict__ x,
                                            const float* __restrict__ Wg,
                                            const unsigned short* __restrict__ At,
                                            unsigned short* __restrict__ Xext) {
    // LDS: xt 32x64 bf16 (4 KB) | at 128x64 bf16 (16 KB) | comb 32x8 f32 (1 KB)
    __shared__ __align__(16) unsigned short lds[2048 + 8192 + 512];
    unsigned short* xt = lds;                 // ushort idx 0
    unsigned short* at = lds + 2048;          // ushort idx 2048 (byte 4096)
    float* comb = (float*)(lds + 2048 + 8192);// byte 20480

    const int t = threadIdx.x;
    const int lane = t & 63;
    const int w = t >> 6;
    const int quad = lane >> 4;
    const int l15 = lane & 15;
    const int bm = blockIdx.x;                // 256 blocks x 32 tokens
    const int n0 = bm * 32;

    const int r   = t >> 3;                   // token row 0..31 (per thread)
    const int c8  = t & 7;                    // LDS seg position
    const int seg = c8 ^ (r & 7);             // global seg this thread handles

    // At staging constants (hall pattern): 4 insts x 32 rows, 8 rows/wave/inst
    const int srow2 = t >> 3;
    const int gseg  = (t & 7) ^ (srow2 & 7);

    f32x4 acc[2][2] = {};
    float gl[NE] = {};

    const float* xp = x + (size_t)(n0 + r) * DM + seg * 8;

    for (int k0 = 0; k0 < DM; k0 += 64) {     // 16 iterations
        __syncthreads();                      // previous iter's readers done
        // x fp32 load (8 floats), gating FMA, convert, stage
        float4 u0 = *(const float4*)(xp + k0);
        float4 u1 = *(const float4*)(xp + k0 + 4);
        #pragma unroll
        for (int e = 0; e < NE; ++e) {
            const float* wp = Wg + (size_t)e * DM + k0 + seg * 8;
            float4 g0 = *(const float4*)wp;
            float4 g1 = *(const float4*)(wp + 4);
            gl[e] += u0.x * g0.x + u0.y * g0.y + u0.z * g0.z + u0.w * g0.w
                   + u1.x * g1.x + u1.y * g1.y + u1.z * g1.z + u1.w * g1.w;
        }
        ushort4 b0, b1;
        b0.x = f2bf(u0.x); b0.y = f2bf(u0.y); b0.z = f2bf(u0.z); b0.w = f2bf(u0.w);
        b1.x = f2bf(u1.x); b1.y = f2bf(u1.y); b1.z = f2bf(u1.z); b1.w = f2bf(u1.w);
        *(ushort4*)&xt[r * 64 + c8 * 8]     = b0;   // LDS pos c8 holds global seg
        *(ushort4*)&xt[r * 64 + c8 * 8 + 4] = b1;
        // x bf16 global writeout (128 B-aligned row chunks, coalesced)
        unsigned short* gx = Xext + (size_t)(n0 + r) * KX + k0 + seg * 8;
        *(ushort4*)gx       = b0;
        *(ushort4*)(gx + 4) = b1;
        // At chunk -> LDS (async, XOR-swizzled)
        #pragma unroll
        for (int rr = 0; rr < 4; ++rr) {
            const unsigned short* g = At + (size_t)(rr * 32 + srow2) * DM + k0 + gseg * 8;
            gld16(g, (char*)at + rr * 4096 + w * 1024);
        }
        __syncthreads();
        // MFMA x @ At^T
        #pragma unroll
        for (int kk = 0; kk < 2; ++kk) {
            const int gs = kk * 4 + quad;
            const int sw = (gs ^ (l15 & 7)) * 8;
            bf16x8 a[2], bb[2];
            #pragma unroll
            for (int i = 0; i < 2; ++i)
                a[i] = *(const bf16x8*)&xt[(i * 16 + l15) * 64 + sw];
            #pragma unroll
            for (int jf = 0; jf < 2; ++jf)
                bb[jf] = *(const bf16x8*)&at[(w * 32 + jf * 16 + l15) * 64 + sw];
            #pragma unroll
            for (int i = 0; i < 2; ++i)
                #pragma unroll
                for (int jf = 0; jf < 2; ++jf)
                    acc[i][jf] = __builtin_amdgcn_mfma_f32_16x16x32_bf16(a[i], bb[jf], acc[i][jf], 0, 0, 0);
        }
    }

    // Gating: butterfly over the 8-lane group sharing token r
    #pragma unroll
    for (int off = 1; off <= 4; off <<= 1)
        #pragma unroll
        for (int e = 0; e < NE; ++e) gl[e] += __shfl_xor(gl[e], off, 64);
    // all 8 lanes of the group hold all 8 logits; lane j writes expert j
    {
        float best = gl[0]; int bi = 0;
        #pragma unroll
        for (int e = 1; e < NE; ++e) if (gl[e] > best) { best = gl[e]; bi = e; }
        float sec = -1e30f; int si = 0;
        #pragma unroll
        for (int e = 0; e < NE; ++e) if (e != bi && gl[e] > sec) { sec = gl[e]; si = e; }
        const float ed = __expf(sec - best);
        const float w0 = 1.f / (1.f + ed);
        const float w1 = ed * w0;
        comb[r * NE + c8] = (c8 == bi) ? w0 : ((c8 == si) ? w1 : 0.f);
    }
    __syncthreads();

    // Scale H by combine, write bf16
    #pragma unroll
    for (int i = 0; i < 2; ++i)
        #pragma unroll
        for (int jf = 0; jf < 2; ++jf) {
            const int col = w * 32 + jf * 16 + l15;
            const int e = col >> 4;
            #pragma unroll
            for (int v = 0; v < 4; ++v) {
                const int nl = i * 16 + quad * 4 + v;
                const float val = acc[i][jf][v] * comb[nl * NE + e];
                Xext[(size_t)(n0 + nl) * KX + DM + col] = f2bf(val);
            }
        }
}

// ---------------------------------------------------------------------------
// mgemm: out[8192][1024] = Xext[8192][1152] @ WBext[1024][1152]^T + bias
//   128x128 tile, BK=128 (9 iters), 64 KB LDS (A [0,32K) | B [32K,64K)),
//   XOR-swizzled K-segments, epilogue LDS-transpose, XCD-aware block decode.
//   (unchanged from R5 — passed at absmax 0.03125)
// ---------------------------------------------------------------------------
__global__ __launch_bounds__(256, 2) void mgemm(const unsigned short* __restrict__ Xext,
                                                const unsigned short* __restrict__ WBext,
                                                const float* __restrict__ bias,
                                                float* __restrict__ out) {
    __shared__ __align__(16) unsigned short lds[32768];   // 64 KB
    const int t = threadIdx.x;
    const int lane = t & 63;
    const int w = t >> 6;
    const int quad = lane >> 4;
    const int l15 = lane & 15;

    const int bid = blockIdx.x;          // 512
    const int xcd = bid & 7;
    const int loc = bid >> 3;
    const int bm = xcd * 8 + (loc & 7);  // 0..63
    const int bn = loc >> 3;             // 0..7

    const int wm = (w & 1) * 64;
    const int wn = (w >> 1) * 64;

    f32x4 acc[4][4] = {};

    const int srow = w * 4 + (lane >> 4);
    const int seg  = (lane & 15) ^ (srow & 7);
    const unsigned short* gA = Xext  + (size_t)(bm * 128 + srow) * KX + seg * 8;
    const unsigned short* gB = WBext + (size_t)(bn * 128 + srow) * KX + seg * 8;
    char* ldsA = (char*)lds + w * 1024;
    char* ldsB = (char*)lds + 32768 + w * 1024;

    for (int k0 = 0; k0 < KX; k0 += 128) {
        __syncthreads();
        #pragma unroll
        for (int c = 0; c < 8; ++c) {
            gld16(gA + (size_t)c * 16 * KX + k0, ldsA + c * 4096);
            gld16(gB + (size_t)c * 16 * KX + k0, ldsB + c * 4096);
        }
        __syncthreads();
        #pragma unroll
        for (int kk = 0; kk < 4; ++kk) {
            const int gs = kk * 4 + quad;
            const int sw = (gs ^ (l15 & 7)) * 8;
            bf16x8 a[4], b[4];
            #pragma unroll
            for (int i = 0; i < 4; ++i)
                a[i] = *(const bf16x8*)&lds[(wm + i * 16 + l15) * 128 + sw];
            #pragma unroll
            for (int j = 0; j < 4; ++j)
                b[j] = *(const bf16x8*)&lds[16384 + (wn + j * 16 + l15) * 128 + sw];
            #pragma unroll
            for (int i = 0; i < 4; ++i)
                #pragma unroll
                for (int j = 0; j < 4; ++j)
                    acc[i][j] = __builtin_amdgcn_mfma_f32_16x16x32_bf16(a[i], b[j], acc[i][j], 0, 0, 0);
        }
    }

    __syncthreads();
    float* lf = (float*)lds + w * 4096;
    #pragma unroll
    for (int j = 0; j < 4; ++j) {
        const float bv = bias[bn * 128 + wn + j * 16 + l15];
        #pragma unroll
        for (int i = 0; i < 4; ++i)
            #pragma unroll
            for (int v = 0; v < 4; ++v) {
                const int row_l = i * 16 + quad * 4 + v;
                const int col_s = (j * 16 + l15) ^ ((row_l & 1) << 4);
                lf[row_l * 64 + col_s] = acc[i][j][v] + bv;
            }
    }
    __builtin_amdgcn_s_waitcnt(0);
    #pragma unroll
    for (int rr = 0; rr < 16; ++rr) {
        const int row_r = rr * 4 + (lane >> 4);
        const int col4  = (lane & 15) * 4;
        const int col4s = col4 ^ ((row_r & 1) << 4);
        float4 vv = *(const float4*)&lf[row_r * 64 + col4s];
        *(float4*)&out[(size_t)(bm * 128 + wm + row_r) * DM + bn * 128 + wn + col4] = vv;
    }
}

// ---------------------------------------------------------------------------
extern "C" void kernel_launch(void* const* d_in, const int* in_sizes, int n_in,
                              void* d_out, int out_size, void* d_ws, size_t ws_size,
                              hipStream_t stream) {
    const float* x  = (const float*)d_in[0];   // [8192,1024]
    const float* Wg = (const float*)d_in[1];   // [8,1024]
    const float* A  = (const float*)d_in[2];   // [8,1024,16]
    const float* B  = (const float*)d_in[3];   // [8,16,1024]
    const float* Wb = (const float*)d_in[4];   // [1024,1024]
    const float* bb = (const float*)d_in[5];   // [1024]
    float* out = (float*)d_out;

    char* ws = (char*)d_ws;
    unsigned short* Xext  = (unsigned short*)ws;                    // 18874368 B
    unsigned short* WBext = (unsigned short*)(ws + 18874368);       // 2359296 B
    unsigned short* At    = (unsigned short*)(ws + 18874368 + 2359296); // 262144 B

    hipLaunchKernelGGL(wprep, dim3(1152), dim3(256), 0, stream, A, B, Wb, WBext, At);
    hipLaunchKernelGGL(gmoe,  dim3(256),  dim3(256), 0, stream, x, Wg, At, Xext);
    hipLaunchKernelGGL(mgemm, dim3(512),  dim3(256), 0, stream, Xext, WBext, bb, out);
}

// Round 7
// 129.144 us; speedup vs baseline: 1.1086x; 1.1086x over previous
//
#include <hip/hip_runtime.h>
#include <stdint.h>

// Problem constants (fixed by reference)
#define NTOK 8192
#define DM   1024
#define NE   8
#define NR   16
#define KX   1152   // DM + NE*NR = 1024 + 128

typedef short bf16x8 __attribute__((ext_vector_type(8)));
typedef float f32x4  __attribute__((ext_vector_type(4)));

__device__ __forceinline__ unsigned short f2bf(float f) {
    union { float f; unsigned u; } v; v.f = f;
    unsigned r = v.u + 0x7fffu + ((v.u >> 16) & 1u);   // RNE
    return (unsigned short)(r >> 16);
}

__device__ __forceinline__ void gld16(const void* g, void* l) {
    __builtin_amdgcn_global_load_lds((__attribute__((address_space(1))) void*)g,
                                     (__attribute__((address_space(3))) void*)l,
                                     16, 0, 0);
}

// ---------------------------------------------------------------------------
// prep: fused role-by-block kernel (R5-proven).
//  blocks [0,2048):     fp32 gating (wave/token) + x -> bf16 into Xext[:,0:1024]
//  blocks [2048,3072):  WBext[j][0:1152] = [W_base[j][:] | B[:, j]]  (bf16)
//  blocks [3072,3200):  At[p][0:1024] = A[e][:][r] transpose        (bf16)
// ---------------------------------------------------------------------------
__global__ __launch_bounds__(256) void prep(const float* __restrict__ x,
                                            const float* __restrict__ Wg,
                                            const float* __restrict__ Asrc,
                                            const float* __restrict__ Bsrc,
                                            const float* __restrict__ Wb,
                                            float* __restrict__ combine,
                                            unsigned short* __restrict__ Xext,
                                            unsigned short* __restrict__ WBext,
                                            unsigned short* __restrict__ At) {
    const int b = blockIdx.x;
    const int t = threadIdx.x;

    if (b < 2048) {
        const int lane = t & 63;
        const int w = t >> 6;
        const int n = b * 4 + w;

        const float4* x4 = (const float4*)(x + (size_t)n * DM);
        float4 xv[4];
        #pragma unroll
        for (int i = 0; i < 4; ++i) xv[i] = x4[i * 64 + lane];

        float acc[NE];
        #pragma unroll
        for (int e = 0; e < NE; ++e) {
            const float4* wg4 = (const float4*)(Wg + (size_t)e * DM);
            float s = 0.f;
            #pragma unroll
            for (int i = 0; i < 4; ++i) {
                float4 g = wg4[i * 64 + lane];
                s += xv[i].x * g.x + xv[i].y * g.y + xv[i].z * g.z + xv[i].w * g.w;
            }
            acc[e] = s;
        }
        #pragma unroll
        for (int off = 32; off >= 1; off >>= 1) {
            #pragma unroll
            for (int e = 0; e < NE; ++e) acc[e] += __shfl_xor(acc[e], off, 64);
        }
        // top-2, lowest index wins ties (matches lax.top_k)
        float best = acc[0]; int bi = 0;
        #pragma unroll
        for (int e = 1; e < NE; ++e) if (acc[e] > best) { best = acc[e]; bi = e; }
        float sec = -1e30f; int si = 0;
        #pragma unroll
        for (int e = 0; e < NE; ++e) if (e != bi && acc[e] > sec) { sec = acc[e]; si = e; }
        const float ed = __expf(sec - best);
        const float w0 = 1.f / (1.f + ed);
        const float w1 = ed * w0;
        if (lane < NE)
            combine[n * NE + lane] = (lane == bi) ? w0 : ((lane == si) ? w1 : 0.f);

        unsigned short* xrow = Xext + (size_t)n * KX;
        #pragma unroll
        for (int i = 0; i < 4; ++i) {
            ushort4 o;
            o.x = f2bf(xv[i].x); o.y = f2bf(xv[i].y);
            o.z = f2bf(xv[i].z); o.w = f2bf(xv[i].w);
            *(ushort4*)(xrow + (i * 64 + lane) * 4) = o;
        }
    } else if (b < 3072) {
        const int j = b - 2048;
        unsigned short* row = WBext + (size_t)j * KX;
        float4 v = ((const float4*)(Wb + (size_t)j * DM))[t];
        ushort4 o;
        o.x = f2bf(v.x); o.y = f2bf(v.y); o.z = f2bf(v.z); o.w = f2bf(v.w);
        *(ushort4*)(row + t * 4) = o;
        if (t < 128) row[DM + t] = f2bf(Bsrc[(size_t)t * DM + j]);   // B[e][r][j]
    } else {
        const int p = b - 3072;
        const int e = p >> 4, r = p & 15;
        for (int d = t; d < DM; d += 256)
            At[(size_t)p * DM + d] = f2bf(Asrc[e * (DM * NR) + d * NR + r]);
    }
}

// ---------------------------------------------------------------------------
// hall: Hfull = (x_bf16 @ At^T) * combine -> bf16 into Xext[:, 1024:1152]
//   512 blocks (32 tokens x 64 cols -> 2 blocks/CU), single-barrier
//   double-buffered K-loop: stage(k+1 -> other buf) issued right after the
//   barrier, compute(k) runs while loads are in flight; next barrier's
//   vmcnt(0) drain lands on loads a full compute-phase old.
// ---------------------------------------------------------------------------
__global__ __launch_bounds__(256) void hall_kernel(unsigned short* Xext,
                                                   const unsigned short* __restrict__ At,
                                                   const float* __restrict__ combine) {
    // per buffer: xt 32x64 bf16 (4 KB) + at 64x64 bf16 (8 KB) = 12 KB; x2 = 24 KB
    __shared__ __align__(16) unsigned short lds[12288];
    const int t = threadIdx.x;
    const int lane = t & 63;
    const int w = t >> 6;
    const int quad = lane >> 4;
    const int l15 = lane & 15;
    const int bid = blockIdx.x;        // 512
    const int bm = bid >> 1;           // token tile 0..255
    const int cb = bid & 1;            // column half 0..1
    const int n0 = bm * 32;
    const int wm = (w & 1) * 16;
    const int wn = (w >> 1) * 32;

    const int srow = t >> 3;                     // 0..31
    const int seg  = (t & 7) ^ (srow & 7);       // XOR swizzle (global side)

    const unsigned short* gX  = Xext + (size_t)(n0 + srow) * KX + seg * 8;
    const unsigned short* gA0 = At + (size_t)(cb * 64 + srow) * DM + seg * 8;
    const unsigned short* gA1 = At + (size_t)(cb * 64 + 32 + srow) * DM + seg * 8;

    f32x4 acc[2] = {};

    // stage(k0, buf s): x -> [s*12KB, +4KB), At -> [s*12KB+4KB, +8KB)
    #define HALL_STAGE(k0, s)                                              \
        gld16(gX  + (k0), (char*)lds + (s) * 12288 + w * 1024);            \
        gld16(gA0 + (k0), (char*)lds + (s) * 12288 + 4096 + w * 1024);     \
        gld16(gA1 + (k0), (char*)lds + (s) * 12288 + 8192 + w * 1024);

    #define HALL_COMPUTE(s)                                                        \
        {                                                                          \
            const int xo = (s) * 6144, ao = (s) * 6144 + 2048;                     \
            _Pragma("unroll")                                                      \
            for (int kk = 0; kk < 2; ++kk) {                                       \
                const int gs = kk * 4 + quad;                                      \
                const int sw = (gs ^ (l15 & 7)) * 8;                               \
                bf16x8 a = *(const bf16x8*)&lds[xo + (wm + l15) * 64 + sw];        \
                _Pragma("unroll")                                                  \
                for (int jf = 0; jf < 2; ++jf) {                                   \
                    bf16x8 bb = *(const bf16x8*)&lds[ao + (wn + jf * 16 + l15) * 64 + sw]; \
                    acc[jf] = __builtin_amdgcn_mfma_f32_16x16x32_bf16(a, bb, acc[jf], 0, 0, 0); \
                }                                                                  \
            }                                                                      \
        }

    HALL_STAGE(0, 0);
    for (int k0 = 0; k0 < DM; k0 += 128) {       // 8 macro-iters (16 chunks)
        __syncthreads();
        HALL_STAGE(k0 + 64, 1);                  // k0+64 <= 960+64 = 1024? guard:
        HALL_COMPUTE(0);
        __syncthreads();
        if (k0 + 128 < DM) { HALL_STAGE(k0 + 128, 0); }
        HALL_COMPUTE(1);
    }
    // NOTE: at k0 = DM-128 the first stage targets k0+64 = DM-64 (valid).

    // Epilogue: scale by combine, write bf16 H
    #pragma unroll
    for (int jf = 0; jf < 2; ++jf) {
        const int p = cb * 64 + wn + jf * 16 + l15;
        const int e = p >> 4;
        #pragma unroll
        for (int v = 0; v < 4; ++v) {
            const int n = n0 + wm + quad * 4 + v;
            const float val = acc[jf][v] * combine[n * NE + e];
            Xext[(size_t)n * KX + DM + p] = f2bf(val);
        }
    }
    #undef HALL_STAGE
    #undef HALL_COMPUTE
}

// ---------------------------------------------------------------------------
// mgemm: out[8192][1024] = Xext[8192][1152] @ WBext[1024][1152]^T + bias
//   128x128 tile, BK=64 double-buffered (A0|B0|A1|B1 = 4x16 KB = 64 KB),
//   SINGLE barrier per K-chunk: stage(k+1) issued post-barrier, compute(k)
//   hides the load latency. XOR-swizzled K-segments, LDS-transpose epilogue,
//   XCD-aware block decode.
// ---------------------------------------------------------------------------
__global__ __launch_bounds__(256, 2) void mgemm(const unsigned short* __restrict__ Xext,
                                                const unsigned short* __restrict__ WBext,
                                                const float* __restrict__ bias,
                                                float* __restrict__ out) {
    __shared__ __align__(16) unsigned short lds[32768];   // 64 KB
    const int t = threadIdx.x;
    const int lane = t & 63;
    const int w = t >> 6;
    const int quad = lane >> 4;
    const int l15 = lane & 15;

    const int bid = blockIdx.x;          // 512
    const int xcd = bid & 7;
    const int loc = bid >> 3;
    const int bm = xcd * 8 + (loc & 7);  // 0..63
    const int bn = loc >> 3;             // 0..7

    const int wm = (w & 1) * 64;
    const int wn = (w >> 1) * 64;

    f32x4 acc[4][4] = {};

    const int srow = t >> 3;                     // 0..31
    const int seg  = (t & 7) ^ (srow & 7);       // XOR swizzle (global side)
    const unsigned short* gA = Xext  + (size_t)(bm * 128 + srow) * KX + seg * 8;
    const unsigned short* gB = WBext + (size_t)(bn * 128 + srow) * KX + seg * 8;

    // stage(k0, s): A rows c*32+srow -> [s*32KB + c*4KB), B -> +16KB
    #define MG_STAGE(k0, s)                                                          \
        _Pragma("unroll")                                                            \
        for (int c = 0; c < 4; ++c) {                                                \
            gld16(gA + (size_t)c * 32 * KX + (k0), (char*)lds + (s) * 32768 + c * 4096 + w * 1024);        \
            gld16(gB + (size_t)c * 32 * KX + (k0), (char*)lds + (s) * 32768 + 16384 + c * 4096 + w * 1024);\
        }

    #define MG_COMPUTE(s)                                                            \
        {                                                                            \
            const int ao = (s) * 16384, bo = (s) * 16384 + 8192;                     \
            _Pragma("unroll")                                                        \
            for (int kk = 0; kk < 2; ++kk) {                                         \
                const int gs = kk * 4 + quad;                                        \
                const int sw = (gs ^ (l15 & 7)) * 8;                                 \
                bf16x8 a[4], b[4];                                                   \
                _Pragma("unroll")                                                    \
                for (int i = 0; i < 4; ++i)                                          \
                    a[i] = *(const bf16x8*)&lds[ao + (wm + i * 16 + l15) * 64 + sw]; \
                _Pragma("unroll")                                                    \
                for (int j = 0; j < 4; ++j)                                          \
                    b[j] = *(const bf16x8*)&lds[bo + (wn + j * 16 + l15) * 64 + sw]; \
                _Pragma("unroll")                                                    \
                for (int i = 0; i < 4; ++i)                                          \
                    _Pragma("unroll")                                                \
                    for (int j = 0; j < 4; ++j)                                      \
                        acc[i][j] = __builtin_amdgcn_mfma_f32_16x16x32_bf16(a[i], b[j], acc[i][j], 0, 0, 0); \
            }                                                                        \
        }

    MG_STAGE(0, 0);
    for (int k0 = 0; k0 < KX; k0 += 128) {       // 9 macro-iters (18 chunks)
        __syncthreads();
        MG_STAGE(k0 + 64, 1);                    // k0+64 <= 1088 < 1152 always
        MG_COMPUTE(0);
        __syncthreads();
        if (k0 + 128 < KX) { MG_STAGE(k0 + 128, 0); }
        MG_COMPUTE(1);
    }
    #undef MG_STAGE
    #undef MG_COMPUTE

    // Epilogue: per-wave 64x64 LDS transpose -> coalesced float4 stores
    __syncthreads();
    float* lf = (float*)lds + w * 4096;
    #pragma unroll
    for (int j = 0; j < 4; ++j) {
        const float bv = bias[bn * 128 + wn + j * 16 + l15];
        #pragma unroll
        for (int i = 0; i < 4; ++i)
            #pragma unroll
            for (int v = 0; v < 4; ++v) {
                const int row_l = i * 16 + quad * 4 + v;
                const int col_s = (j * 16 + l15) ^ ((row_l & 1) << 4);
                lf[row_l * 64 + col_s] = acc[i][j][v] + bv;
            }
    }
    __builtin_amdgcn_s_waitcnt(0);
    #pragma unroll
    for (int rr = 0; rr < 16; ++rr) {
        const int row_r = rr * 4 + (lane >> 4);
        const int col4  = (lane & 15) * 4;
        const int col4s = col4 ^ ((row_r & 1) << 4);
        float4 vv = *(const float4*)&lf[row_r * 64 + col4s];
        *(float4*)&out[(size_t)(bm * 128 + wm + row_r) * DM + bn * 128 + wn + col4] = vv;
    }
}

// ---------------------------------------------------------------------------
extern "C" void kernel_launch(void* const* d_in, const int* in_sizes, int n_in,
                              void* d_out, int out_size, void* d_ws, size_t ws_size,
                              hipStream_t stream) {
    const float* x  = (const float*)d_in[0];   // [8192,1024]
    const float* Wg = (const float*)d_in[1];   // [8,1024]
    const float* A  = (const float*)d_in[2];   // [8,1024,16]
    const float* B  = (const float*)d_in[3];   // [8,16,1024]
    const float* Wb = (const float*)d_in[4];   // [1024,1024]
    const float* bb = (const float*)d_in[5];   // [1024]
    float* out = (float*)d_out;

    char* ws = (char*)d_ws;
    float*          combine = (float*)ws;                                   // 262144 B
    unsigned short* Xext    = (unsigned short*)(ws + 262144);               // 18874368 B
    unsigned short* WBext   = (unsigned short*)(ws + 262144 + 18874368);    // 2359296 B
    unsigned short* At      = (unsigned short*)(ws + 262144 + 18874368 + 2359296); // 262144 B

    hipLaunchKernelGGL(prep,        dim3(3200), dim3(256), 0, stream,
                       x, Wg, A, B, Wb, combine, Xext, WBext, At);
    hipLaunchKernelGGL(hall_kernel, dim3(512),  dim3(256), 0, stream, Xext, At, combine);
    hipLaunchKernelGGL(mgemm,       dim3(512),  dim3(256), 0, stream, Xext, WBext, bb, out);
}